// Round 1
// baseline (1582.507 us; speedup 1.0000x reference)
//
#include <hip/hip_runtime.h>
#include <math.h>

// Problem constants (match reference)
#define BB 8
#define SS 2048
#define TT 2048
#define ITERS 20
#define EPS_INV 10.0f          // 1/EPSILON
#define NCHUNK 16
#define CHUNK_S (SS / NCHUNK)  // 128

__device__ __forceinline__ void lse_update(float x, float& m, float& s) {
    // online logsumexp accumulate; branchy: max-update is rare after warmup
    if (x <= m) {
        s += __expf(x - m);
    } else {
        s = s * __expf(m - x) + 1.0f;
        m = x;
    }
}

__global__ __launch_bounds__(256) void init_logs(const float* __restrict__ mu,
                                                 const float* __restrict__ nu,
                                                 float* __restrict__ log_mu,
                                                 float* __restrict__ log_nu,
                                                 float* __restrict__ log_u,
                                                 float* __restrict__ log_v) {
    int i = blockIdx.x * 256 + threadIdx.x;  // 0 .. B*S-1 (== B*T-1)
    if (i < BB * SS) {
        log_mu[i] = __logf(fmaxf(mu[i], 1.17549435e-38f));
        log_nu[i] = __logf(fmaxf(nu[i], 1.17549435e-38f));
        log_u[i] = 0.0f;
        log_v[i] = 0.0f;
    }
}

// One wave per (b,s) row: log_u[b,s] = log_mu[b,s] - LSE_t(-cost/eps + log_v[b,t])
__global__ __launch_bounds__(256) void row_update(const float* __restrict__ cost,
                                                  const float* __restrict__ log_mu,
                                                  const float* __restrict__ log_v,
                                                  float* __restrict__ log_u) {
    int wave = threadIdx.x >> 6;
    int lane = threadIdx.x & 63;
    int row = blockIdx.x * 4 + wave;        // 0 .. B*S-1
    int b = row >> 11;                      // / S
    const float* crow = cost + (size_t)row * TT;
    const float* lvrow = log_v + (size_t)b * TT;

    float m = -INFINITY, sum = 0.0f;
#pragma unroll
    for (int i = 0; i < TT / 256; ++i) {    // 8 iterations, float4 per lane
        int idx = (i * 64 + lane) * 4;
        float4 c = *reinterpret_cast<const float4*>(crow + idx);
        float4 v = *reinterpret_cast<const float4*>(lvrow + idx);
        lse_update(fmaf(-EPS_INV, c.x, v.x), m, sum);
        lse_update(fmaf(-EPS_INV, c.y, v.y), m, sum);
        lse_update(fmaf(-EPS_INV, c.z, v.z), m, sum);
        lse_update(fmaf(-EPS_INV, c.w, v.w), m, sum);
    }
    // wave-wide butterfly combine of (m, sum)
#pragma unroll
    for (int off = 1; off < 64; off <<= 1) {
        float mo = __shfl_xor(m, off);
        float so = __shfl_xor(sum, off);
        float mn = fmaxf(m, mo);
        sum = sum * __expf(m - mn) + so * __expf(mo - mn);
        m = mn;
    }
    if (lane == 0) {
        log_u[row] = log_mu[row] - (m + __logf(sum));
    }
}

// Column partial LSE over a chunk of S: thread owns one column t.
// grid = B * (T/256) * NCHUNK
__global__ __launch_bounds__(256) void col_partial(const float* __restrict__ cost,
                                                   const float* __restrict__ log_u,
                                                   float2* __restrict__ partial) {
    int bid = blockIdx.x;
    int chunk = bid & (NCHUNK - 1);
    int tmp = bid >> 4;                     // log2(NCHUNK)
    int ttile = tmp & 7;                    // T/256 = 8
    int b = tmp >> 3;
    int t = ttile * 256 + threadIdx.x;
    int s0 = chunk * CHUNK_S;

    const float* cbase = cost + ((size_t)(b * SS + s0)) * TT + t;
    const float* lu = log_u + b * SS + s0;

    float m = -INFINITY, sum = 0.0f;
#pragma unroll 4
    for (int s = 0; s < CHUNK_S; ++s) {
        float x = fmaf(-EPS_INV, cbase[(size_t)s * TT], lu[s]);
        lse_update(x, m, sum);
    }
    partial[((size_t)(b * TT + t)) * NCHUNK + chunk] = make_float2(m, sum);
}

// Fold NCHUNK partials per column: log_v[b,t] = log_nu[b,t] - LSE
__global__ __launch_bounds__(256) void col_combine(const float2* __restrict__ partial,
                                                   const float* __restrict__ log_nu,
                                                   float* __restrict__ log_v) {
    int i = blockIdx.x * 256 + threadIdx.x;  // 0 .. B*T-1
    if (i >= BB * TT) return;
    const float2* p = partial + (size_t)i * NCHUNK;
    float m = -INFINITY, sum = 0.0f;
#pragma unroll
    for (int c = 0; c < NCHUNK; ++c) {
        float2 ps = p[c];
        float mn = fmaxf(m, ps.x);
        sum = sum * __expf(m - mn) + ps.y * __expf(ps.x - mn);
        m = mn;
    }
    log_v[i] = log_nu[i] - (m + __logf(sum));
}

// transport = exp(log_pi), log_pi = log_u + (-cost/eps) + log_v
__global__ __launch_bounds__(256) void finalize(const float* __restrict__ cost,
                                                const float* __restrict__ log_u,
                                                const float* __restrict__ log_v,
                                                float* __restrict__ transport,
                                                float* __restrict__ log_pi) {
    int i = blockIdx.x * 256 + threadIdx.x;  // float4 index, 0 .. B*S*T/4-1
    int flat = i * 4;
    int row = flat >> 11;                    // / T
    int t = flat & (TT - 1);
    int b = row >> 11;                       // / S

    float lu = log_u[row];
    float4 lv = *reinterpret_cast<const float4*>(log_v + (size_t)b * TT + t);
    float4 c = *reinterpret_cast<const float4*>(cost + (size_t)row * TT + t);

    float4 lp;
    lp.x = fmaf(-EPS_INV, c.x, lu + lv.x);
    lp.y = fmaf(-EPS_INV, c.y, lu + lv.y);
    lp.z = fmaf(-EPS_INV, c.z, lu + lv.z);
    lp.w = fmaf(-EPS_INV, c.w, lu + lv.w);

    float4 tr;
    tr.x = __expf(lp.x);
    tr.y = __expf(lp.y);
    tr.z = __expf(lp.z);
    tr.w = __expf(lp.w);

    *reinterpret_cast<float4*>(transport + (size_t)row * TT + t) = tr;
    *reinterpret_cast<float4*>(log_pi + (size_t)row * TT + t) = lp;
}

extern "C" void kernel_launch(void* const* d_in, const int* in_sizes, int n_in,
                              void* d_out, int out_size, void* d_ws, size_t ws_size,
                              hipStream_t stream) {
    const float* cost = (const float*)d_in[0];
    const float* mu = (const float*)d_in[1];
    const float* nu = (const float*)d_in[2];

    float* out = (float*)d_out;
    float* transport = out;
    float* log_pi = out + (size_t)BB * SS * TT;

    float* ws = (float*)d_ws;
    float* log_mu = ws;                 // 16384
    float* log_nu = ws + 16384;         // 16384
    float* log_u = ws + 32768;          // 16384
    float* log_v = ws + 49152;          // 16384
    float2* partial = (float2*)(ws + 65536);  // B*T*NCHUNK float2 = 2 MiB

    hipLaunchKernelGGL(init_logs, dim3(64), dim3(256), 0, stream,
                       mu, nu, log_mu, log_nu, log_u, log_v);

    for (int it = 0; it < ITERS; ++it) {
        hipLaunchKernelGGL(row_update, dim3(BB * SS / 4), dim3(256), 0, stream,
                           cost, log_mu, log_v, log_u);
        hipLaunchKernelGGL(col_partial, dim3(BB * (TT / 256) * NCHUNK), dim3(256), 0, stream,
                           cost, log_u, partial);
        hipLaunchKernelGGL(col_combine, dim3(BB * TT / 256), dim3(256), 0, stream,
                           partial, log_nu, log_v);
    }

    hipLaunchKernelGGL(finalize, dim3(BB * SS * TT / 4 / 256), dim3(256), 0, stream,
                       cost, log_u, log_v, transport, log_pi);
}

// Round 2
// 1419.844 us; speedup vs baseline: 1.1146x; 1.1146x over previous
//
#include <hip/hip_runtime.h>
#include <math.h>

// Problem constants (match reference)
#define BB 8
#define SS 2048
#define TT 2048
#define ITERS 20
#define NEG_EPS_INV -10.0f     // -1/EPSILON
#define ROWS 16
#define NTILE (SS / ROWS)      // 128

__device__ __forceinline__ float4 fma4v(float a, float4 x, float4 y) {
    return make_float4(fmaf(a, x.x, y.x), fmaf(a, x.y, y.y),
                       fmaf(a, x.z, y.z), fmaf(a, x.w, y.w));
}
__device__ __forceinline__ float4 fma4s(float a, float4 x, float s) {
    return make_float4(fmaf(a, x.x, s), fmaf(a, x.y, s),
                       fmaf(a, x.z, s), fmaf(a, x.w, s));
}
__device__ __forceinline__ float4 max4(float4 a, float4 b) {
    return make_float4(fmaxf(a.x, b.x), fmaxf(a.y, b.y),
                       fmaxf(a.z, b.z), fmaxf(a.w, b.w));
}

__global__ __launch_bounds__(256) void init_logs(const float* __restrict__ mu,
                                                 const float* __restrict__ nu,
                                                 float* __restrict__ log_mu,
                                                 float* __restrict__ log_nu,
                                                 float* __restrict__ log_v) {
    int i = blockIdx.x * 256 + threadIdx.x;  // 0 .. B*S-1 (== B*T-1)
    if (i < BB * SS) {
        log_mu[i] = __logf(fmaxf(mu[i], 1.17549435e-38f));
        log_nu[i] = __logf(fmaxf(nu[i], 1.17549435e-38f));
        log_v[i] = 0.0f;   // v_0 = 0
    }
}

// Fused iteration kernel. Block owns a 16-row x 2048-col strip of cost[b].
// Phase 1: log_u for its 16 rows (row-LSE with log_v).
// Phase 2: column partial LSEs over its 16 rows using the fresh log_u.
// Strip lives in registers: thread t holds float4 columns {t, t+256} of all 16 rows.
__global__ __launch_bounds__(256, 2) void fused_pass(
        const float* __restrict__ cost, const float* __restrict__ log_mu,
        const float* __restrict__ log_v, float* __restrict__ log_u,
        float* __restrict__ colm, float* __restrict__ cols) {
    int t = threadIdx.x;
    int tile = blockIdx.x;
    int b = blockIdx.y;
    int row0 = tile * ROWS;

    const float4* strip4 = (const float4*)(cost + ((size_t)(b * SS + row0)) * TT);
    const float4* lv4 = (const float4*)(log_v + (size_t)b * TT);
    float4 va = lv4[t];
    float4 vb = lv4[t + 256];

    float4 reg[2 * ROWS];
#pragma unroll
    for (int i = 0; i < 2 * ROWS; ++i) reg[i] = strip4[i * 256 + t];

    // ---- Phase 1a: per-thread per-row max of x = -cost/eps + log_v ----
    float pm[ROWS];
#pragma unroll
    for (int r = 0; r < ROWS; ++r) {
        float4 xa = fma4v(NEG_EPS_INV, reg[2 * r], va);
        float4 xb = fma4v(NEG_EPS_INV, reg[2 * r + 1], vb);
        float4 m4 = max4(xa, xb);
        pm[r] = fmaxf(fmaxf(m4.x, m4.y), fmaxf(m4.z, m4.w));
    }
    // wave butterfly max
#pragma unroll
    for (int r = 0; r < ROWS; ++r) {
#pragma unroll
        for (int off = 1; off < 64; off <<= 1)
            pm[r] = fmaxf(pm[r], __shfl_xor(pm[r], off));
    }
    __shared__ float ldsa[4 * ROWS];
    __shared__ float ldsb[4 * ROWS];
    int wave = t >> 6, lane = t & 63;
    if (lane == 0) {
#pragma unroll
        for (int r = 0; r < ROWS; ++r) ldsa[wave * ROWS + r] = pm[r];
    }
    __syncthreads();
    float M[ROWS];
#pragma unroll
    for (int r = 0; r < ROWS; ++r)
        M[r] = fmaxf(fmaxf(ldsa[r], ldsa[ROWS + r]),
                     fmaxf(ldsa[2 * ROWS + r], ldsa[3 * ROWS + r]));

    // ---- Phase 1b: per-thread per-row sum of exp(x - M) ----
    float ps[ROWS];
#pragma unroll
    for (int r = 0; r < ROWS; ++r) {
        float4 xa = fma4v(NEG_EPS_INV, reg[2 * r], va);
        float4 xb = fma4v(NEG_EPS_INV, reg[2 * r + 1], vb);
        ps[r] = __expf(xa.x - M[r]) + __expf(xa.y - M[r]) +
                __expf(xa.z - M[r]) + __expf(xa.w - M[r]) +
                __expf(xb.x - M[r]) + __expf(xb.y - M[r]) +
                __expf(xb.z - M[r]) + __expf(xb.w - M[r]);
    }
#pragma unroll
    for (int r = 0; r < ROWS; ++r) {
#pragma unroll
        for (int off = 1; off < 64; off <<= 1)
            ps[r] += __shfl_xor(ps[r], off);
    }
    if (lane == 0) {
#pragma unroll
        for (int r = 0; r < ROWS; ++r) ldsb[wave * ROWS + r] = ps[r];
    }
    __syncthreads();

    // u[r] = log_mu - (M + log(sum)), computed redundantly by all threads
    float u[ROWS];
    const float* lmu = log_mu + b * SS + row0;
#pragma unroll
    for (int r = 0; r < ROWS; ++r) {
        float ssum = ldsb[r] + ldsb[ROWS + r] + ldsb[2 * ROWS + r] + ldsb[3 * ROWS + r];
        u[r] = lmu[r] - (M[r] + __logf(ssum));
    }
    // write log_u (static-index trick: avoid runtime-indexed register array)
    float uo = 0.0f;
#pragma unroll
    for (int r = 0; r < ROWS; ++r)
        if (t == r) uo = u[r];
    if (t < ROWS) log_u[b * SS + row0 + t] = uo;

    // ---- Phase 2: column partials over the 16 in-register rows ----
    float4 cmA = make_float4(-INFINITY, -INFINITY, -INFINITY, -INFINITY);
    float4 cmB = cmA;
#pragma unroll
    for (int r = 0; r < ROWS; ++r) {
        cmA = max4(cmA, fma4s(NEG_EPS_INV, reg[2 * r], u[r]));
        cmB = max4(cmB, fma4s(NEG_EPS_INV, reg[2 * r + 1], u[r]));
    }
    float4 csA = make_float4(0.f, 0.f, 0.f, 0.f);
    float4 csB = csA;
#pragma unroll
    for (int r = 0; r < ROWS; ++r) {
        float4 xa = fma4s(NEG_EPS_INV, reg[2 * r], u[r]);
        float4 xb = fma4s(NEG_EPS_INV, reg[2 * r + 1], u[r]);
        csA.x += __expf(xa.x - cmA.x); csA.y += __expf(xa.y - cmA.y);
        csA.z += __expf(xa.z - cmA.z); csA.w += __expf(xa.w - cmA.w);
        csB.x += __expf(xb.x - cmB.x); csB.y += __expf(xb.y - cmB.y);
        csB.z += __expf(xb.z - cmB.z); csB.w += __expf(xb.w - cmB.w);
    }
    float4* cm4 = (float4*)colm + (size_t)(tile * BB + b) * (TT / 4);
    float4* cs4 = (float4*)cols + (size_t)(tile * BB + b) * (TT / 4);
    cm4[t] = cmA; cm4[t + 256] = cmB;
    cs4[t] = csA; cs4[t + 256] = csB;
}

// Fold NTILE partials per column: log_v[b,t] = log_nu - LSE.
// Block: 4 waves x 64 cols; wave w folds tiles [w*32, w*32+32); LDS-combine.
__global__ __launch_bounds__(256) void combine_v(
        const float* __restrict__ colm, const float* __restrict__ cols,
        const float* __restrict__ log_nu, float* __restrict__ log_v) {
    int tid = threadIdx.x;
    int seg = tid >> 6;
    int ci = tid & 63;
    int col = blockIdx.x * 64 + ci;   // grid.x = TT/64
    int b = blockIdx.y;

    float m = -INFINITY, s = 0.0f;
#pragma unroll 4
    for (int k = 0; k < NTILE / 4; ++k) {
        int tile = seg * (NTILE / 4) + k;
        size_t idx = (size_t)(tile * BB + b) * TT + col;
        float lm = colm[idx];
        float ls = cols[idx];
        float mn = fmaxf(m, lm);
        s = s * __expf(m - mn) + ls * __expf(lm - mn);
        m = mn;
    }
    __shared__ float lmlds[4][64];
    __shared__ float lslds[4][64];
    lmlds[seg][ci] = m;
    lslds[seg][ci] = s;
    __syncthreads();
    if (tid < 64) {
        float mm = lmlds[0][ci], ss = lslds[0][ci];
#pragma unroll
        for (int w = 1; w < 4; ++w) {
            float lm = lmlds[w][ci], ls = lslds[w][ci];
            float mn = fmaxf(mm, lm);
            ss = ss * __expf(mm - mn) + ls * __expf(lm - mn);
            mm = mn;
        }
        int i = b * TT + col;
        log_v[i] = log_nu[i] - (mm + __logf(ss));
    }
}

// transport = exp(log_pi), log_pi = log_u + (-cost/eps) + log_v
__global__ __launch_bounds__(256) void finalize(const float* __restrict__ cost,
                                                const float* __restrict__ log_u,
                                                const float* __restrict__ log_v,
                                                float* __restrict__ transport,
                                                float* __restrict__ log_pi) {
    int i = blockIdx.x * 256 + threadIdx.x;  // float4 index
    int flat = i * 4;
    int row = flat >> 11;                    // / T
    int t = flat & (TT - 1);
    int b = row >> 11;                       // / S

    float lu = log_u[row];
    float4 lv = *reinterpret_cast<const float4*>(log_v + (size_t)b * TT + t);
    float4 c = *reinterpret_cast<const float4*>(cost + (size_t)row * TT + t);

    float4 lp;
    lp.x = fmaf(NEG_EPS_INV, c.x, lu + lv.x);
    lp.y = fmaf(NEG_EPS_INV, c.y, lu + lv.y);
    lp.z = fmaf(NEG_EPS_INV, c.z, lu + lv.z);
    lp.w = fmaf(NEG_EPS_INV, c.w, lu + lv.w);

    float4 tr;
    tr.x = __expf(lp.x);
    tr.y = __expf(lp.y);
    tr.z = __expf(lp.z);
    tr.w = __expf(lp.w);

    *reinterpret_cast<float4*>(transport + (size_t)row * TT + t) = tr;
    *reinterpret_cast<float4*>(log_pi + (size_t)row * TT + t) = lp;
}

extern "C" void kernel_launch(void* const* d_in, const int* in_sizes, int n_in,
                              void* d_out, int out_size, void* d_ws, size_t ws_size,
                              hipStream_t stream) {
    const float* cost = (const float*)d_in[0];
    const float* mu = (const float*)d_in[1];
    const float* nu = (const float*)d_in[2];

    float* out = (float*)d_out;
    float* transport = out;
    float* log_pi = out + (size_t)BB * SS * TT;

    float* ws = (float*)d_ws;
    float* log_mu = ws;                 // 16384 floats
    float* log_nu = ws + 16384;
    float* log_u = ws + 32768;
    float* log_v = ws + 49152;

    // Partial planes live in d_out's transport region as scratch (finalize
    // fully overwrites d_out afterwards): NTILE*BB*TT = 2.1M floats each.
    float* colm = out;
    float* cols = out + (1 << 22);      // 4M-float offset, well inside 33.5M region

    hipLaunchKernelGGL(init_logs, dim3(64), dim3(256), 0, stream,
                       mu, nu, log_mu, log_nu, log_v);

    for (int it = 0; it < ITERS; ++it) {
        hipLaunchKernelGGL(fused_pass, dim3(NTILE, BB), dim3(256), 0, stream,
                           cost, log_mu, log_v, log_u, colm, cols);
        hipLaunchKernelGGL(combine_v, dim3(TT / 64, BB), dim3(256), 0, stream,
                           colm, cols, log_nu, log_v);
    }

    hipLaunchKernelGGL(finalize, dim3(BB * SS * TT / 4 / 256), dim3(256), 0, stream,
                       cost, log_u, log_v, transport, log_pi);
}

// Round 3
// 689.716 us; speedup vs baseline: 2.2944x; 2.0586x over previous
//
#include <hip/hip_runtime.h>
#include <math.h>

// Problem constants (match reference)
#define BB 8
#define SS 2048
#define TT 2048
#define ITERS 20
#define NEG_EPS_INV -10.0f     // -1/EPSILON
#define RPW 2                  // rows per wave
#define NWAVE 4
#define ROWS (RPW * NWAVE)     // 8 rows per block
#define NTILE (SS / ROWS)      // 256 tiles
#define TINYF 1.17549435e-38f

__device__ __forceinline__ float4 fma4v(float a, float4 x, float4 y) {
    return make_float4(fmaf(a, x.x, y.x), fmaf(a, x.y, y.y),
                       fmaf(a, x.z, y.z), fmaf(a, x.w, y.w));
}
__device__ __forceinline__ float4 max4(float4 a, float4 b) {
    return make_float4(fmaxf(a.x, b.x), fmaxf(a.y, b.y),
                       fmaxf(a.z, b.z), fmaxf(a.w, b.w));
}
__device__ __forceinline__ float hmax4(float4 a) {
    return fmaxf(fmaxf(a.x, a.y), fmaxf(a.z, a.w));
}
__device__ __forceinline__ float hsum4(float4 a) {
    return (a.x + a.y) + (a.z + a.w);
}
__device__ __forceinline__ float4 exp4m(float4 x, float m) {
    return make_float4(__expf(x.x - m), __expf(x.y - m),
                       __expf(x.z - m), __expf(x.w - m));
}

__global__ __launch_bounds__(256) void init_logv(float* __restrict__ log_v) {
    log_v[blockIdx.x * 256 + threadIdx.x] = 0.0f;   // grid = BB*TT/256
}

// One iteration, fused. Block owns 8 rows x 2048 cols of cost[b]; each wave
// owns 2 full rows (row LSE entirely in-wave). Column partials are PLAIN SUMS:
//   P[tile,t] = sum_r exp(x_row[r,t] - M_r) * (mu_r / ssum_r)
// using  LSE_col(t) = -v_t + log(sum_tiles P),  so no col max, no 2nd exp.
__global__ __launch_bounds__(256, 3) void fused_pass(
        const float* __restrict__ cost, const float* __restrict__ mu,
        const float* __restrict__ log_v, float* __restrict__ log_u,
        float* __restrict__ P) {
    int t = threadIdx.x;
    int w = t >> 6, l = t & 63;
    int tile = blockIdx.x, b = blockIdx.y;
    int r0 = tile * ROWS + w * RPW;          // row within batch b (wave's 1st row)

    const float4* c4 = (const float4*)(cost + (size_t)b * SS * TT);
    const float4* v4 = (const float4*)(log_v + (size_t)b * TT);

    // v for this lane's 8 column-chunks (reused by both rows)
    float4 vv[8];
#pragma unroll
    for (int i = 0; i < 8; ++i) vv[i] = v4[i * 64 + l];

    // load both rows, fold into x = -cost/eps + v  (cost regs overwritten)
    float4 x0[8], x1[8];
#pragma unroll
    for (int i = 0; i < 8; ++i) x0[i] = c4[((size_t)r0) * 512 + i * 64 + l];
#pragma unroll
    for (int i = 0; i < 8; ++i) x1[i] = c4[((size_t)r0 + 1) * 512 + i * 64 + l];
#pragma unroll
    for (int i = 0; i < 8; ++i) {
        x0[i] = fma4v(NEG_EPS_INV, x0[i], vv[i]);
        x1[i] = fma4v(NEG_EPS_INV, x1[i], vv[i]);
    }

    // row max (in-wave butterfly)
    float4 a0 = x0[0], a1 = x1[0];
#pragma unroll
    for (int i = 1; i < 8; ++i) { a0 = max4(a0, x0[i]); a1 = max4(a1, x1[i]); }
    float m0 = hmax4(a0), m1 = hmax4(a1);
#pragma unroll
    for (int off = 1; off < 64; off <<= 1) {
        m0 = fmaxf(m0, __shfl_xor(m0, off));
        m1 = fmaxf(m1, __shfl_xor(m1, off));
    }

    // e = exp(x - M) in place; row sums
    float ps0 = 0.0f, ps1 = 0.0f;
#pragma unroll
    for (int i = 0; i < 8; ++i) {
        x0[i] = exp4m(x0[i], m0);
        x1[i] = exp4m(x1[i], m1);
        ps0 += hsum4(x0[i]);
        ps1 += hsum4(x1[i]);
    }
#pragma unroll
    for (int off = 1; off < 64; off <<= 1) {
        ps0 += __shfl_xor(ps0, off);
        ps1 += __shfl_xor(ps1, off);
    }

    // g = mu/ssum;  u = log(g) - M   (ssum >= 1 always)
    float g0 = mu[b * SS + r0] / ps0;
    float g1 = mu[b * SS + r0 + 1] / ps1;
    if (l == 0) {
        log_u[b * SS + r0]     = __logf(fmaxf(g0, TINYF)) - m0;
        log_u[b * SS + r0 + 1] = __logf(fmaxf(g1, TINYF)) - m1;
    }

    // column partial: cs = e0*g0 + e1*g1  (pure fma)
    __shared__ float4 lds[NWAVE][512];
#pragma unroll
    for (int i = 0; i < 8; ++i) {
        float4 cs;
        cs.x = fmaf(g0, x0[i].x, g1 * x1[i].x);
        cs.y = fmaf(g0, x0[i].y, g1 * x1[i].y);
        cs.z = fmaf(g0, x0[i].z, g1 * x1[i].z);
        cs.w = fmaf(g0, x0[i].w, g1 * x1[i].w);
        lds[w][i * 64 + l] = cs;
    }
    __syncthreads();

    // cross-wave sum -> one 2048-col plane per block
    float4* P4 = (float4*)P + (size_t)(tile * BB + b) * 512;
#pragma unroll
    for (int k = 0; k < 2; ++k) {
        int j = k * 256 + t;
        float4 s0 = lds[0][j], s1 = lds[1][j], s2 = lds[2][j], s3 = lds[3][j];
        float4 o;
        o.x = (s0.x + s1.x) + (s2.x + s3.x);
        o.y = (s0.y + s1.y) + (s2.y + s3.y);
        o.z = (s0.z + s1.z) + (s2.z + s3.z);
        o.w = (s0.w + s1.w) + (s2.w + s3.w);
        P4[j] = o;
    }
}

// log_v_new[b,t] = log_nu + v_old - log(sum_tiles P[tile,b,t])
// Block: 4 segs x 64 cols; seg folds 64 tiles; LDS combine.
__global__ __launch_bounds__(256) void combine_v(
        const float* __restrict__ P, const float* __restrict__ nu,
        float* __restrict__ log_v) {
    int t = threadIdx.x;
    int seg = t >> 6, ci = t & 63;
    int col = blockIdx.x * 64 + ci;     // grid.x = TT/64
    int b = blockIdx.y;

    float s = 0.0f;
#pragma unroll 8
    for (int k = 0; k < NTILE / 4; ++k) {
        int tile = seg * (NTILE / 4) + k;
        s += P[((size_t)tile * BB + b) * TT + col];
    }
    __shared__ float lds[4][64];
    lds[seg][ci] = s;
    __syncthreads();
    if (t < 64) {
        float tot = (lds[0][ci] + lds[1][ci]) + (lds[2][ci] + lds[3][ci]);
        int i = b * TT + col;
        log_v[i] = __logf(fmaxf(nu[i], TINYF)) + log_v[i] - __logf(fmaxf(tot, TINYF));
    }
}

// transport = exp(log_pi), log_pi = log_u + (-cost/eps) + log_v
__global__ __launch_bounds__(256) void finalize(const float* __restrict__ cost,
                                                const float* __restrict__ log_u,
                                                const float* __restrict__ log_v,
                                                float* __restrict__ transport,
                                                float* __restrict__ log_pi) {
    int i = blockIdx.x * 256 + threadIdx.x;  // float4 index
    int flat = i * 4;
    int row = flat >> 11;                    // / T
    int t = flat & (TT - 1);
    int b = row >> 11;                       // / S

    float lu = log_u[row];
    float4 lv = *reinterpret_cast<const float4*>(log_v + (size_t)b * TT + t);
    float4 c = *reinterpret_cast<const float4*>(cost + (size_t)row * TT + t);

    float4 lp;
    lp.x = fmaf(NEG_EPS_INV, c.x, lu + lv.x);
    lp.y = fmaf(NEG_EPS_INV, c.y, lu + lv.y);
    lp.z = fmaf(NEG_EPS_INV, c.z, lu + lv.z);
    lp.w = fmaf(NEG_EPS_INV, c.w, lu + lv.w);

    float4 tr;
    tr.x = __expf(lp.x);
    tr.y = __expf(lp.y);
    tr.z = __expf(lp.z);
    tr.w = __expf(lp.w);

    *reinterpret_cast<float4*>(transport + (size_t)row * TT + t) = tr;
    *reinterpret_cast<float4*>(log_pi + (size_t)row * TT + t) = lp;
}

extern "C" void kernel_launch(void* const* d_in, const int* in_sizes, int n_in,
                              void* d_out, int out_size, void* d_ws, size_t ws_size,
                              hipStream_t stream) {
    const float* cost = (const float*)d_in[0];
    const float* mu = (const float*)d_in[1];
    const float* nu = (const float*)d_in[2];

    float* out = (float*)d_out;
    float* transport = out;
    float* log_pi = out + (size_t)BB * SS * TT;

    float* ws = (float*)d_ws;
    float* log_u = ws;                  // 16384 floats
    float* log_v = ws + 16384;          // 16384 floats

    // P partial planes (NTILE*BB*TT floats = 16.8 MB) live in d_out's
    // transport region as scratch; finalize fully overwrites d_out afterwards.
    float* P = out;

    hipLaunchKernelGGL(init_logv, dim3(BB * TT / 256), dim3(256), 0, stream, log_v);

    for (int it = 0; it < ITERS; ++it) {
        hipLaunchKernelGGL(fused_pass, dim3(NTILE, BB), dim3(256), 0, stream,
                           cost, mu, log_v, log_u, P);
        hipLaunchKernelGGL(combine_v, dim3(TT / 64, BB), dim3(256), 0, stream,
                           P, nu, log_v);
    }

    hipLaunchKernelGGL(finalize, dim3(BB * SS * TT / 4 / 256), dim3(256), 0, stream,
                       cost, log_u, log_v, transport, log_pi);
}

// Round 4
// 508.067 us; speedup vs baseline: 3.1148x; 1.3575x over previous
//
#include <hip/hip_runtime.h>
#include <hip/hip_fp16.h>
#include <math.h>

// Problem constants (match reference)
#define BB 8
#define SS 2048
#define TT 2048
#define ITERS 20
#define NEG_EPS_INV -10.0f     // -1/EPSILON
#define RPW 2                  // rows per wave
#define NWAVE 4
#define ROWS (RPW * NWAVE)     // 8 rows per block
#define NTILE (SS / ROWS)      // 256 tiles
#define TINYF 1.17549435e-38f

__device__ __forceinline__ float4 fma4v(float a, float4 x, float4 y) {
    return make_float4(fmaf(a, x.x, y.x), fmaf(a, x.y, y.y),
                       fmaf(a, x.z, y.z), fmaf(a, x.w, y.w));
}
__device__ __forceinline__ float4 max4(float4 a, float4 b) {
    return make_float4(fmaxf(a.x, b.x), fmaxf(a.y, b.y),
                       fmaxf(a.z, b.z), fmaxf(a.w, b.w));
}
__device__ __forceinline__ float hmax4(float4 a) {
    return fmaxf(fmaxf(a.x, a.y), fmaxf(a.z, a.w));
}
__device__ __forceinline__ float hsum4(float4 a) {
    return (a.x + a.y) + (a.z + a.w);
}
__device__ __forceinline__ float4 exp4m(float4 x, float m) {
    return make_float4(__expf(x.x - m), __expf(x.y - m),
                       __expf(x.z - m), __expf(x.w - m));
}
__device__ __forceinline__ uint h2u(__half2 h) {
    union { __half2 h; uint u; } c; c.h = h; return c.u;
}
__device__ __forceinline__ __half2 u2h(uint u) {
    union { __half2 h; uint u; } c; c.u = u; return c.h;
}
__device__ __forceinline__ uint2 pack4(float4 f) {
    uint2 r;
    r.x = h2u(__float22half2_rn(make_float2(f.x, f.y)));
    r.y = h2u(__float22half2_rn(make_float2(f.z, f.w)));
    return r;
}
__device__ __forceinline__ float4 unpack4(uint2 u) {
    float2 a = __half22float2(u2h(u.x));
    float2 b = __half22float2(u2h(u.y));
    return make_float4(a.x, a.y, b.x, b.y);
}

__global__ __launch_bounds__(256) void init_logv(float* __restrict__ log_v) {
    log_v[blockIdx.x * 256 + threadIdx.x] = 0.0f;   // grid = BB*TT/256
}

// One fused Sinkhorn iteration. Block owns 8 rows x 2048 cols of cost[b];
// each wave owns 2 full rows (row LSE entirely in-wave). Column partials are
// plain sums: P[tile,t] = sum_r exp(x[r,t]-M_r) * (mu_r/ssum_r), so
// v_new = log_nu + v_old - log(sum_tiles P).
// FIRST variant reads fp32 cost and emits the fp16 cache as a side product;
// later iterations read the fp16 cache (half the bytes).
template <bool FIRST>
__global__ __launch_bounds__(256, 3) void fused_pass(
        const float* __restrict__ cost, const uint2* __restrict__ c16r,
        uint2* __restrict__ c16w, const float* __restrict__ mu,
        const float* __restrict__ log_v, float* __restrict__ log_u,
        float* __restrict__ P) {
    int t = threadIdx.x;
    int w = t >> 6, l = t & 63;
    int tile = blockIdx.x, b = blockIdx.y;
    int r0 = tile * ROWS + w * RPW;          // wave's first row within batch b

    size_t rowbase = (size_t)(b * SS + r0) * TT;   // elements
    const float4* v4 = (const float4*)(log_v + (size_t)b * TT);

    // v for this lane's 8 column-chunks (shared by both rows)
    float4 vv[8];
#pragma unroll
    for (int i = 0; i < 8; ++i) vv[i] = v4[i * 64 + l];

    float4 x0[8], x1[8];
    if constexpr (FIRST) {
        const float4* c4 = (const float4*)(cost + rowbase);
        uint2* cw = c16w + rowbase / 4;      // uint2 = 4 halves
#pragma unroll
        for (int i = 0; i < 8; ++i) x0[i] = c4[i * 64 + l];
#pragma unroll
        for (int i = 0; i < 8; ++i) x1[i] = c4[512 + i * 64 + l];
#pragma unroll
        for (int i = 0; i < 8; ++i) {
            cw[i * 64 + l] = pack4(x0[i]);
            cw[512 + i * 64 + l] = pack4(x1[i]);
        }
    } else {
        const uint2* cr = c16r + rowbase / 4;
#pragma unroll
        for (int i = 0; i < 8; ++i) x0[i] = unpack4(cr[i * 64 + l]);
#pragma unroll
        for (int i = 0; i < 8; ++i) x1[i] = unpack4(cr[512 + i * 64 + l]);
    }
#pragma unroll
    for (int i = 0; i < 8; ++i) {
        x0[i] = fma4v(NEG_EPS_INV, x0[i], vv[i]);
        x1[i] = fma4v(NEG_EPS_INV, x1[i], vv[i]);
    }

    // row max (in-wave butterfly)
    float4 a0 = x0[0], a1 = x1[0];
#pragma unroll
    for (int i = 1; i < 8; ++i) { a0 = max4(a0, x0[i]); a1 = max4(a1, x1[i]); }
    float m0 = hmax4(a0), m1 = hmax4(a1);
#pragma unroll
    for (int off = 1; off < 64; off <<= 1) {
        m0 = fmaxf(m0, __shfl_xor(m0, off));
        m1 = fmaxf(m1, __shfl_xor(m1, off));
    }

    // e = exp(x - M) in place; row sums
    float ps0 = 0.0f, ps1 = 0.0f;
#pragma unroll
    for (int i = 0; i < 8; ++i) {
        x0[i] = exp4m(x0[i], m0);
        x1[i] = exp4m(x1[i], m1);
        ps0 += hsum4(x0[i]);
        ps1 += hsum4(x1[i]);
    }
#pragma unroll
    for (int off = 1; off < 64; off <<= 1) {
        ps0 += __shfl_xor(ps0, off);
        ps1 += __shfl_xor(ps1, off);
    }

    // g = mu/ssum;  u = log(g) - M
    float g0 = mu[b * SS + r0] / ps0;
    float g1 = mu[b * SS + r0 + 1] / ps1;
    if (l == 0) {
        log_u[b * SS + r0]     = __logf(fmaxf(g0, TINYF)) - m0;
        log_u[b * SS + r0 + 1] = __logf(fmaxf(g1, TINYF)) - m1;
    }

    // column partial: cs = e0*g0 + e1*g1 (pure fma), cross-wave sum via LDS
    __shared__ float4 lds[NWAVE][512];
#pragma unroll
    for (int i = 0; i < 8; ++i) {
        float4 cs;
        cs.x = fmaf(g0, x0[i].x, g1 * x1[i].x);
        cs.y = fmaf(g0, x0[i].y, g1 * x1[i].y);
        cs.z = fmaf(g0, x0[i].z, g1 * x1[i].z);
        cs.w = fmaf(g0, x0[i].w, g1 * x1[i].w);
        lds[w][i * 64 + l] = cs;
    }
    __syncthreads();

    float4* P4 = (float4*)P + (size_t)(tile * BB + b) * 512;
#pragma unroll
    for (int k = 0; k < 2; ++k) {
        int j = k * 256 + t;
        float4 s0 = lds[0][j], s1 = lds[1][j], s2 = lds[2][j], s3 = lds[3][j];
        float4 o;
        o.x = (s0.x + s1.x) + (s2.x + s3.x);
        o.y = (s0.y + s1.y) + (s2.y + s3.y);
        o.z = (s0.z + s1.z) + (s2.z + s3.z);
        o.w = (s0.w + s1.w) + (s2.w + s3.w);
        P4[j] = o;
    }
}

// log_v_new[b,t] = log_nu + v_old - log(sum_tiles P[tile,b,t])
__global__ __launch_bounds__(256) void combine_v(
        const float* __restrict__ P, const float* __restrict__ nu,
        float* __restrict__ log_v) {
    int t = threadIdx.x;
    int seg = t >> 6, ci = t & 63;
    int col = blockIdx.x * 64 + ci;     // grid.x = TT/64
    int b = blockIdx.y;

    float s = 0.0f;
#pragma unroll 8
    for (int k = 0; k < NTILE / 4; ++k) {
        int tile = seg * (NTILE / 4) + k;
        s += P[((size_t)tile * BB + b) * TT + col];
    }
    __shared__ float lds[4][64];
    lds[seg][ci] = s;
    __syncthreads();
    if (t < 64) {
        float tot = (lds[0][ci] + lds[1][ci]) + (lds[2][ci] + lds[3][ci]);
        int i = b * TT + col;
        log_v[i] = __logf(fmaxf(nu[i], TINYF)) + log_v[i] - __logf(fmaxf(tot, TINYF));
    }
}

// transport = exp(log_pi), log_pi = log_u + (-cost/eps) + log_v  (exact fp32 cost)
__global__ __launch_bounds__(256) void finalize(const float* __restrict__ cost,
                                                const float* __restrict__ log_u,
                                                const float* __restrict__ log_v,
                                                float* __restrict__ transport,
                                                float* __restrict__ log_pi) {
    int i = blockIdx.x * 256 + threadIdx.x;  // float4 index
    int flat = i * 4;
    int row = flat >> 11;                    // / T
    int t = flat & (TT - 1);
    int b = row >> 11;                       // / S

    float lu = log_u[row];
    float4 lv = *reinterpret_cast<const float4*>(log_v + (size_t)b * TT + t);
    float4 c = *reinterpret_cast<const float4*>(cost + (size_t)row * TT + t);

    float4 lp;
    lp.x = fmaf(NEG_EPS_INV, c.x, lu + lv.x);
    lp.y = fmaf(NEG_EPS_INV, c.y, lu + lv.y);
    lp.z = fmaf(NEG_EPS_INV, c.z, lu + lv.z);
    lp.w = fmaf(NEG_EPS_INV, c.w, lu + lv.w);

    float4 tr;
    tr.x = __expf(lp.x);
    tr.y = __expf(lp.y);
    tr.z = __expf(lp.z);
    tr.w = __expf(lp.w);

    *reinterpret_cast<float4*>(transport + (size_t)row * TT + t) = tr;
    *reinterpret_cast<float4*>(log_pi + (size_t)row * TT + t) = lp;
}

extern "C" void kernel_launch(void* const* d_in, const int* in_sizes, int n_in,
                              void* d_out, int out_size, void* d_ws, size_t ws_size,
                              hipStream_t stream) {
    const float* cost = (const float*)d_in[0];
    const float* mu = (const float*)d_in[1];
    const float* nu = (const float*)d_in[2];

    float* out = (float*)d_out;
    float* transport = out;
    float* log_pi = out + (size_t)BB * SS * TT;

    // Scratch layout in d_ws (~1 GiB observed): vectors, P planes, fp16 cache.
    float* ws = (float*)d_ws;
    float* log_u = ws;                       // 16K floats
    float* log_v = ws + 16384;               // 16K floats
    float* P = ws + (1 << 20);               // 4 MB offset; NTILE*BB*TT fl = 16.8 MB
    uint2* c16 = (uint2*)(ws + (1 << 23));   // 32 MB offset; B*S*T halves = 67 MB

    hipLaunchKernelGGL(init_logv, dim3(BB * TT / 256), dim3(256), 0, stream, log_v);

    hipLaunchKernelGGL((fused_pass<true>), dim3(NTILE, BB), dim3(256), 0, stream,
                       cost, c16, c16, mu, log_v, log_u, P);
    hipLaunchKernelGGL(combine_v, dim3(TT / 64, BB), dim3(256), 0, stream,
                       P, nu, log_v);

    for (int it = 1; it < ITERS; ++it) {
        hipLaunchKernelGGL((fused_pass<false>), dim3(NTILE, BB), dim3(256), 0, stream,
                           cost, c16, c16, mu, log_v, log_u, P);
        hipLaunchKernelGGL(combine_v, dim3(TT / 64, BB), dim3(256), 0, stream,
                           P, nu, log_v);
    }

    hipLaunchKernelGGL(finalize, dim3(BB * SS * TT / 4 / 256), dim3(256), 0, stream,
                       cost, log_u, log_v, transport, log_pi);
}